// Round 1
// baseline (389.669 us; speedup 1.0000x reference)
//
#include <hip/hip_runtime.h>

// SphereConv: N=2, CIN=64, COUT=64, H=256, W=512, K=3 (K2=9)
// out[n,o,h,w] = sum_{c,k} weight[o,c,k] * bilinear(x[n,c], pos[k,:,h,w])
// Round 0: fp32 vector-ALU baseline. One thread per pixel, acc[64] over COUT,
// weights pre-transposed to wT[k][c][o] so the inner 64-FMA loop reads them as
// wave-uniform scalars (s_load, SGPR operand to v_fmac_f32).

constexpr int N_ = 2;
constexpr int CIN = 64;
constexpr int COUT = 64;
constexpr int H_ = 256;
constexpr int W_ = 512;
constexpr int K2 = 9;
constexpr int HW = H_ * W_;

__global__ void transpose_w_kernel(const float* __restrict__ w, float* __restrict__ wT) {
  int i = blockIdx.x * blockDim.x + threadIdx.x;
  if (i < COUT * CIN * K2) {
    int k = i % K2;
    int c = (i / K2) % CIN;
    int o = i / (K2 * CIN);
    wT[(k * CIN + c) * COUT + o] = w[i];
  }
}

__global__ __launch_bounds__(256) void sphere_conv_kernel(
    const float* __restrict__ x, const float* __restrict__ wT,
    const float* __restrict__ pos, float* __restrict__ out) {
  int idx = blockIdx.x * blockDim.x + threadIdx.x;  // 0 .. N*HW-1
  int n = idx / HW;
  int hw = idx - n * HW;
  const float* xb = x + n * CIN * HW;

  float acc[COUT];
#pragma unroll
  for (int o = 0; o < COUT; ++o) acc[o] = 0.f;

  for (int k = 0; k < K2; ++k) {
    // positions: pos[2k] = lat (py), pos[2k+1] = lon (px), each an (H,W) map
    float py = pos[(2 * k + 0) * HW + hw];
    float px = pos[(2 * k + 1) * HW + hw];
    float y0f = floorf(py), x0f = floorf(px);
    float dy = py - y0f, dx = px - x0f;
    float y1f = y0f + 1.f, x1f = x0f + 1.f;

    // validity exactly as reference: corner zeroed if outside [0, H-1]/[0, W-1]
    float vy0 = (y0f >= 0.f && y0f <= (float)(H_ - 1)) ? 1.f : 0.f;
    float vy1 = (y1f >= 0.f && y1f <= (float)(H_ - 1)) ? 1.f : 0.f;
    float vx0 = (x0f >= 0.f && x0f <= (float)(W_ - 1)) ? 1.f : 0.f;
    float vx1 = (x1f >= 0.f && x1f <= (float)(W_ - 1)) ? 1.f : 0.f;

    float w00 = (1.f - dy) * (1.f - dx) * vy0 * vx0;
    float w01 = (1.f - dy) * dx * vy0 * vx1;
    float w10 = dy * (1.f - dx) * vy1 * vx0;
    float w11 = dy * dx * vy1 * vx1;

    // clip-then-cast, matching jnp.clip(...).astype(int32)
    int y0c = (int)fminf(fmaxf(y0f, 0.f), (float)(H_ - 1));
    int y1c = (int)fminf(fmaxf(y1f, 0.f), (float)(H_ - 1));
    int x0c = (int)fminf(fmaxf(x0f, 0.f), (float)(W_ - 1));
    int x1c = (int)fminf(fmaxf(x1f, 0.f), (float)(W_ - 1));

    int o00 = y0c * W_ + x0c;
    int o01 = y0c * W_ + x1c;
    int o10 = y1c * W_ + x0c;
    int o11 = y1c * W_ + x1c;

    const float* wk = wT + k * CIN * COUT;
    const float* xc = xb;
    for (int c = 0; c < CIN; ++c) {
      float s = w00 * xc[o00] + w01 * xc[o01] + w10 * xc[o10] + w11 * xc[o11];
      const float* wrow = wk + c * COUT;  // wave-uniform address -> s_load
#pragma unroll
      for (int o = 0; o < COUT; ++o) acc[o] = fmaf(wrow[o], s, acc[o]);
      xc += HW;
    }
  }

#pragma unroll
  for (int o = 0; o < COUT; ++o) out[(n * COUT + o) * HW + hw] = acc[o];
}

extern "C" void kernel_launch(void* const* d_in, const int* in_sizes, int n_in,
                              void* d_out, int out_size, void* d_ws, size_t ws_size,
                              hipStream_t stream) {
  const float* x   = (const float*)d_in[0];  // (N, CIN, H, W) fp32
  const float* w   = (const float*)d_in[1];  // (COUT, CIN, 3, 3) fp32
  const float* pos = (const float*)d_in[2];  // (18, H, W) fp32
  float* out = (float*)d_out;                // (N, COUT, H, W) fp32
  float* wT = (float*)d_ws;                  // 36864 floats = 147 KiB scratch

  int wn = COUT * CIN * K2;
  transpose_w_kernel<<<(wn + 255) / 256, 256, 0, stream>>>(w, wT);

  int total = N_ * HW;  // 262144 pixels
  sphere_conv_kernel<<<total / 256, 256, 0, stream>>>(x, wT, pos, out);
}

// Round 2
// 283.452 us; speedup vs baseline: 1.3747x; 1.3747x over previous
//
#include <hip/hip_runtime.h>
#include <hip/hip_bf16.h>

// SphereConv N=2, CIN=64, COUT=64, H=256, W=512, K2=9.
// Round 1: fused bf16-MFMA. out[n,:,p] = W[64x576] @ S[576x128] per 128-px tile,
// K ordered tap-major (K = tap*64 + c) so each 32-wide K-step is one tap.
// S tile gathered+bilinear'd into LDS per step; W pre-transposed to bf16 in ws
// laid out for direct per-lane 16B A-frag loads (L2-resident, reloaded per step).

constexpr int N_ = 2;
constexpr int CIN = 64;
constexpr int COUT = 64;
constexpr int H_ = 256;
constexpr int W_ = 512;
constexpr int K2 = 9;
constexpr int HW = H_ * W_;
constexpr int NSTEP = (CIN * K2) / 32;  // 18
constexpr int PTILE = 128;
constexpr int SROW = 40;  // sbuf row stride in bf16 elems (32 + 8 pad, keeps 16B align)

typedef __attribute__((ext_vector_type(8))) short short8;
typedef __attribute__((ext_vector_type(4))) float floatx4;

// wTr[(wv*18 + s)*64*8 + lane*8 + j] = bf16(weight[o = 16wv + (lane&15)]
//                                           [kk = 32s + (lane>>4)*8 + j])
// with kk -> tap = kk>>6, c = kk&63; weight flat (o*CIN + c)*9 + tap.
__global__ void prep_w(const float* __restrict__ w, ushort* __restrict__ wTr) {
  int i = blockIdx.x * blockDim.x + threadIdx.x;
  if (i >= 4 * NSTEP * 64 * 8) return;
  int j = i & 7;
  int lane = (i >> 3) & 63;
  int s = (i >> 9) % NSTEP;
  int wv = i / (512 * NSTEP);
  int o = wv * 16 + (lane & 15);
  int kk = s * 32 + (lane >> 4) * 8 + j;
  int tap = kk >> 6, c = kk & 63;
  __hip_bfloat16 b = __float2bfloat16(w[(o * CIN + c) * K2 + tap]);
  wTr[i] = *(ushort*)&b;
}

__global__ __launch_bounds__(256, 3) void sphere_conv_mfma(
    const float* __restrict__ x, const ushort* __restrict__ wTr,
    const float* __restrict__ pos, float* __restrict__ out) {
  __shared__ int4 off_lds[K2 * PTILE];     // 18 KB: 4 corner elem-offsets
  __shared__ float4 wgt_lds[K2 * PTILE];   // 18 KB: 4 corner weights
  __shared__ ushort sbuf[PTILE * SROW];    // 10 KB: S tile [px][kk], bf16

  int tid = threadIdx.x;
  int blk = blockIdx.x;
  int n = blk >> 10;                  // HW/PTILE = 1024 tiles per batch
  int ptile = (blk & 1023) * PTILE;

  // ---- phase 0: bilinear offsets/weights for 9 taps x 128 pixels ----
  for (int i = tid; i < K2 * PTILE; i += 256) {
    int t = i / PTILE, p = i - t * PTILE;
    int hw = ptile + p;
    float py = pos[(2 * t + 0) * HW + hw];
    float px = pos[(2 * t + 1) * HW + hw];
    float y0f = floorf(py), x0f = floorf(px);
    float dy = py - y0f, dx = px - x0f;
    float y1f = y0f + 1.f, x1f = x0f + 1.f;
    float vy0 = (y0f >= 0.f && y0f <= (float)(H_ - 1)) ? 1.f : 0.f;
    float vy1 = (y1f >= 0.f && y1f <= (float)(H_ - 1)) ? 1.f : 0.f;
    float vx0 = (x0f >= 0.f && x0f <= (float)(W_ - 1)) ? 1.f : 0.f;
    float vx1 = (x1f >= 0.f && x1f <= (float)(W_ - 1)) ? 1.f : 0.f;
    float w00 = (1.f - dy) * (1.f - dx) * vy0 * vx0;
    float w01 = (1.f - dy) * dx * vy0 * vx1;
    float w10 = dy * (1.f - dx) * vy1 * vx0;
    float w11 = dy * dx * vy1 * vx1;
    int y0c = (int)fminf(fmaxf(y0f, 0.f), (float)(H_ - 1));
    int y1c = (int)fminf(fmaxf(y1f, 0.f), (float)(H_ - 1));
    int x0c = (int)fminf(fmaxf(x0f, 0.f), (float)(W_ - 1));
    int x1c = (int)fminf(fmaxf(x1f, 0.f), (float)(W_ - 1));
    off_lds[i] = make_int4(y0c * W_ + x0c, y0c * W_ + x1c,
                           y1c * W_ + x0c, y1c * W_ + x1c);
    wgt_lds[i] = make_float4(w00, w01, w10, w11);
  }

  int lane = tid & 63, wv = tid >> 6;
  int col = lane & 15, quad = lane >> 4;
  int p_s = tid & 127, cb = tid >> 7;  // sampling: pixel p_s, channel half cb

  floatx4 acc[8];
#pragma unroll
  for (int nt = 0; nt < 8; ++nt) acc[nt] = (floatx4)0.f;

  __syncthreads();

  for (int s = 0; s < NSTEP; ++s) {
    // A-frag: 16B per lane from ws (L2-resident), issued early to hide latency
    short8 afrag = *(const short8*)(wTr + ((wv * NSTEP + s) * 64 + lane) * 8);

    // ---- sampling: S[kk=0..31][p=0..127] for tap t, channels c0..c0+31 ----
    int t = s >> 1;
    int c0 = (s & 1) * 32;
    int4 o4 = off_lds[t * PTILE + p_s];
    float4 wgt = wgt_lds[t * PTILE + p_s];
    const float* xb = x + (size_t)(n * CIN + c0 + cb * 16) * HW;
    __align__(16) ushort tmp[16];
#pragma unroll
    for (int ci = 0; ci < 16; ++ci) {
      float sv = wgt.x * xb[o4.x] + wgt.y * xb[o4.y] +
                 wgt.z * xb[o4.z] + wgt.w * xb[o4.w];
      __hip_bfloat16 hb = __float2bfloat16(sv);
      tmp[ci] = *(ushort*)&hb;
      xb += HW;
    }
    uint4* dst = (uint4*)&sbuf[p_s * SROW + cb * 16];
    dst[0] = *((const uint4*)tmp + 0);
    dst[1] = *((const uint4*)tmp + 1);
    __syncthreads();

    // ---- MFMA: wave wv covers COUT rows [16wv,16wv+16) x 128 px ----
#pragma unroll
    for (int nt = 0; nt < 8; ++nt) {
      short8 bfrag = *(const short8*)&sbuf[(nt * 16 + col) * SROW + quad * 8];
      acc[nt] = __builtin_amdgcn_mfma_f32_16x16x32_bf16(afrag, bfrag, acc[nt], 0, 0, 0);
    }
    __syncthreads();  // protect sbuf before next step's writes
  }

  // ---- epilogue: D row = quad*4+r (COUT), col = lane&15 (pixel) ----
#pragma unroll
  for (int nt = 0; nt < 8; ++nt) {
#pragma unroll
    for (int r = 0; r < 4; ++r) {
      int o = wv * 16 + quad * 4 + r;
      out[(size_t)(n * COUT + o) * HW + ptile + nt * 16 + col] = acc[nt][r];
    }
  }
}

extern "C" void kernel_launch(void* const* d_in, const int* in_sizes, int n_in,
                              void* d_out, int out_size, void* d_ws, size_t ws_size,
                              hipStream_t stream) {
  const float* x   = (const float*)d_in[0];  // (2, 64, 256, 512) fp32
  const float* w   = (const float*)d_in[1];  // (64, 64, 3, 3) fp32
  const float* pos = (const float*)d_in[2];  // (18, 256, 512) fp32
  float* out = (float*)d_out;                // (2, 64, 256, 512) fp32
  ushort* wTr = (ushort*)d_ws;               // 36864 bf16 = 72 KB

  prep_w<<<(4 * NSTEP * 64 * 8 + 255) / 256, 256, 0, stream>>>(w, wTr);

  int nblk = N_ * (HW / PTILE);  // 2048
  sphere_conv_mfma<<<nblk, 256, 0, stream>>>(x, wTr, pos, out);
}

// Round 3
// 210.825 us; speedup vs baseline: 1.8483x; 1.3445x over previous
//
#include <hip/hip_runtime.h>
#include <hip/hip_bf16.h>

// SphereConv N=2, CIN=64, COUT=64, H=256, W=512, K2=9.
// Round 2: channel-last bf16 gather. x is transposed to xt[n][hw][c] (bf16,
// 67 MB in d_ws, L3-resident) so one bilinear corner = 128 B contiguous.
// Gather per thread per K-step: 8x 16B loads (was 64 scattered dwords).
// MFMA structure unchanged from round 1 (verified correct).

constexpr int N_ = 2;
constexpr int CIN = 64;
constexpr int COUT = 64;
constexpr int H_ = 256;
constexpr int W_ = 512;
constexpr int K2 = 9;
constexpr int HW = H_ * W_;
constexpr int NSTEP = (CIN * K2) / 32;  // 18
constexpr int PTILE = 128;
constexpr int SROW = 40;  // sbuf row stride (32 + 8 pad, keeps 16B align)

typedef __attribute__((ext_vector_type(8))) short short8;
typedef __attribute__((ext_vector_type(4))) float floatx4;

__device__ __forceinline__ float bf2f(ushort u) {
  return __uint_as_float(((unsigned)u) << 16);
}

// wTr[(wv*18 + s)*64*8 + lane*8 + j] = bf16(weight[o = 16wv + (lane&15)]
//                                           [kk = 32s + (lane>>4)*8 + j])
__global__ void prep_w(const float* __restrict__ w, ushort* __restrict__ wTr) {
  int i = blockIdx.x * blockDim.x + threadIdx.x;
  if (i >= 4 * NSTEP * 64 * 8) return;
  int j = i & 7;
  int lane = (i >> 3) & 63;
  int s = (i >> 9) % NSTEP;
  int wv = i / (512 * NSTEP);
  int o = wv * 16 + (lane & 15);
  int kk = s * 32 + (lane >> 4) * 8 + j;
  int tap = kk >> 6, c = kk & 63;
  __hip_bfloat16 b = __float2bfloat16(w[(o * CIN + c) * K2 + tap]);
  wTr[i] = *(ushort*)&b;
}

// x[n][c][hw] fp32 -> xt[n][hw][c] bf16, via LDS tile (64 px x 64 ch).
__global__ __launch_bounds__(256) void transpose_x(
    const float* __restrict__ x, ushort* __restrict__ xt) {
  __shared__ ushort tile[64 * 72];  // stride 72 keeps 16B-aligned rows
  int b = blockIdx.x;          // n*2048 + hwtile
  int n = b >> 11;             // HW/64 = 2048 tiles
  int hw0 = (b & 2047) * 64;
  int tid = threadIdx.x;
  int px = tid & 63, c4 = tid >> 6;
  const float* xn = x + (size_t)n * CIN * HW;
#pragma unroll
  for (int it = 0; it < 16; ++it) {
    int c = it * 4 + c4;
    float v = xn[(size_t)c * HW + hw0 + px];
    __hip_bfloat16 hb = __float2bfloat16(v);
    tile[px * 72 + c] = *(ushort*)&hb;
  }
  __syncthreads();
  ushort* xtn = xt + (size_t)n * HW * CIN;
#pragma unroll
  for (int it = 0; it < 2; ++it) {
    int task = it * 256 + tid;
    int px2 = task >> 3, chunk = task & 7;
    uint4 v = *(uint4*)&tile[px2 * 72 + chunk * 8];
    *(uint4*)&xtn[(size_t)(hw0 + px2) * 64 + chunk * 8] = v;
  }
}

__global__ __launch_bounds__(256, 4) void sphere_conv_mfma(
    const ushort* __restrict__ xt, const ushort* __restrict__ wTr,
    const float* __restrict__ pos, float* __restrict__ out) {
  __shared__ int off_lds[K2 * PTILE];      // 4.6 KB: packed o00|dx<<20|dy<<21
  __shared__ float4 wgt_lds[K2 * PTILE];   // 18.4 KB: 4 corner weights
  __shared__ ushort sbuf[PTILE * SROW];    // 10 KB: S tile [px][kk], bf16

  int tid = threadIdx.x;
  int blk = blockIdx.x;
  int n = blk >> 10;                  // HW/PTILE = 1024 tiles per batch
  int ptile = (blk & 1023) * PTILE;

  // ---- phase 0: bilinear offsets/weights for 9 taps x 128 pixels ----
  for (int i = tid; i < K2 * PTILE; i += 256) {
    int t = i / PTILE, p = i - t * PTILE;
    int hw = ptile + p;
    float py = pos[(2 * t + 0) * HW + hw];
    float px = pos[(2 * t + 1) * HW + hw];
    float y0f = floorf(py), x0f = floorf(px);
    float dy = py - y0f, dx = px - x0f;
    float y1f = y0f + 1.f, x1f = x0f + 1.f;
    float vy0 = (y0f >= 0.f && y0f <= (float)(H_ - 1)) ? 1.f : 0.f;
    float vy1 = (y1f >= 0.f && y1f <= (float)(H_ - 1)) ? 1.f : 0.f;
    float vx0 = (x0f >= 0.f && x0f <= (float)(W_ - 1)) ? 1.f : 0.f;
    float vx1 = (x1f >= 0.f && x1f <= (float)(W_ - 1)) ? 1.f : 0.f;
    float w00 = (1.f - dy) * (1.f - dx) * vy0 * vx0;
    float w01 = (1.f - dy) * dx * vy0 * vx1;
    float w10 = dy * (1.f - dx) * vy1 * vx0;
    float w11 = dy * dx * vy1 * vx1;
    int y0c = (int)fminf(fmaxf(y0f, 0.f), (float)(H_ - 1));
    int y1c = (int)fminf(fmaxf(y1f, 0.f), (float)(H_ - 1));
    int x0c = (int)fminf(fmaxf(x0f, 0.f), (float)(W_ - 1));
    int x1c = (int)fminf(fmaxf(x1f, 0.f), (float)(W_ - 1));
    int o00 = y0c * W_ + x0c;
    int dx1 = x1c - x0c;   // 0 or 1
    int dy1 = y1c - y0c;   // 0 or 1
    off_lds[i] = o00 | (dx1 << 20) | (dy1 << 21);
    wgt_lds[i] = make_float4(w00, w01, w10, w11);
  }

  int lane = tid & 63, wv = tid >> 6;
  int col = lane & 15, quad = lane >> 4;
  int px_s = tid >> 1, hf = tid & 1;  // sampling: pixel, channel-16 half

  floatx4 acc[8];
#pragma unroll
  for (int nt = 0; nt < 8; ++nt) acc[nt] = (floatx4)0.f;

  const ushort* xtn = xt + (size_t)n * HW * CIN;

  __syncthreads();

  for (int s = 0; s < NSTEP; ++s) {
    // A-frag: 16B per lane from ws (L2-resident)
    short8 afrag = *(const short8*)(wTr + ((wv * NSTEP + s) * 64 + lane) * 8);

    // ---- sampling: S[kk=0..31][p=0..127], tap t, 16 ch per thread ----
    int t = s >> 1;
    int c0 = (s & 1) * 32 + hf * 16;
    int pk = off_lds[t * PTILE + px_s];
    float4 wgt = wgt_lds[t * PTILE + px_s];
    int o00 = pk & 0x1FFFF;
    int dx1 = (pk >> 20) & 1;
    int dyW = ((pk >> 21) & 1) * W_;
    const ushort* base = xtn + c0;
    const ushort* p00 = base + (size_t)o00 * 64;
    const ushort* p01 = base + (size_t)(o00 + dx1) * 64;
    const ushort* p10 = base + (size_t)(o00 + dyW) * 64;
    const ushort* p11 = base + (size_t)(o00 + dyW + dx1) * 64;
    short8 v0a = *(const short8*)p00, v0b = *(const short8*)(p00 + 8);
    short8 v1a = *(const short8*)p01, v1b = *(const short8*)(p01 + 8);
    short8 v2a = *(const short8*)p10, v2b = *(const short8*)(p10 + 8);
    short8 v3a = *(const short8*)p11, v3b = *(const short8*)(p11 + 8);

    float sv[16];
#pragma unroll
    for (int j = 0; j < 8; ++j) {
      sv[j]     = wgt.x * bf2f((ushort)v0a[j]);
      sv[8 + j] = wgt.x * bf2f((ushort)v0b[j]);
      sv[j]     = fmaf(wgt.y, bf2f((ushort)v1a[j]), sv[j]);
      sv[8 + j] = fmaf(wgt.y, bf2f((ushort)v1b[j]), sv[8 + j]);
      sv[j]     = fmaf(wgt.z, bf2f((ushort)v2a[j]), sv[j]);
      sv[8 + j] = fmaf(wgt.z, bf2f((ushort)v2b[j]), sv[8 + j]);
      sv[j]     = fmaf(wgt.w, bf2f((ushort)v3a[j]), sv[j]);
      sv[8 + j] = fmaf(wgt.w, bf2f((ushort)v3b[j]), sv[8 + j]);
    }
    __align__(16) ushort tmp[16];
#pragma unroll
    for (int j = 0; j < 16; ++j) {
      __hip_bfloat16 hb = __float2bfloat16(sv[j]);
      tmp[j] = *(ushort*)&hb;
    }
    uint4* dst = (uint4*)&sbuf[px_s * SROW + hf * 16];
    dst[0] = ((const uint4*)tmp)[0];
    dst[1] = ((const uint4*)tmp)[1];
    __syncthreads();

    // ---- MFMA: wave wv covers COUT rows [16wv,16wv+16) x 128 px ----
#pragma unroll
    for (int nt = 0; nt < 8; ++nt) {
      short8 bfrag = *(const short8*)&sbuf[(nt * 16 + col) * SROW + quad * 8];
      acc[nt] = __builtin_amdgcn_mfma_f32_16x16x32_bf16(afrag, bfrag, acc[nt], 0, 0, 0);
    }
    __syncthreads();
  }

  // ---- epilogue: D row = quad*4+r (COUT), col = lane&15 (pixel) ----
#pragma unroll
  for (int nt = 0; nt < 8; ++nt) {
#pragma unroll
    for (int r = 0; r < 4; ++r) {
      int o = wv * 16 + quad * 4 + r;
      out[(size_t)(n * COUT + o) * HW + ptile + nt * 16 + col] = acc[nt][r];
    }
  }
}

extern "C" void kernel_launch(void* const* d_in, const int* in_sizes, int n_in,
                              void* d_out, int out_size, void* d_ws, size_t ws_size,
                              hipStream_t stream) {
  const float* x   = (const float*)d_in[0];  // (2, 64, 256, 512) fp32
  const float* w   = (const float*)d_in[1];  // (64, 64, 3, 3) fp32
  const float* pos = (const float*)d_in[2];  // (18, 256, 512) fp32
  float* out = (float*)d_out;                // (2, 64, 256, 512) fp32

  // ws layout: wTr bf16 [72 KB] at 0; xt bf16 [67.1 MB] at 128 KB.
  ushort* wTr = (ushort*)d_ws;
  ushort* xt = (ushort*)((char*)d_ws + (128 << 10));

  prep_w<<<(4 * NSTEP * 64 * 8 + 255) / 256, 256, 0, stream>>>(w, wTr);
  transpose_x<<<N_ * (HW / 64), 256, 0, stream>>>(x, xt);

  int nblk = N_ * (HW / PTILE);  // 2048
  sphere_conv_mfma<<<nblk, 256, 0, stream>>>(xt, wTr, pos, out);
}

// Round 4
// 210.504 us; speedup vs baseline: 1.8511x; 1.0015x over previous
//
#include <hip/hip_runtime.h>
#include <hip/hip_bf16.h>

// SphereConv N=2, CIN=64, COUT=64, H=256, W=512, K2=9.
// Round 3: latency attack. Double-buffered sbuf (1 barrier/step, was 2),
// register prefetch of next step's gathers, pk_fma_f32 interp, bf16 interp
// weights in LDS (33.8 KB total). Gather source xt[n][hw][c] bf16 as round 2.

constexpr int N_ = 2;
constexpr int CIN = 64;
constexpr int COUT = 64;
constexpr int H_ = 256;
constexpr int W_ = 512;
constexpr int K2 = 9;
constexpr int HW = H_ * W_;
constexpr int NSTEP = (CIN * K2) / 32;  // 18
constexpr int PTILE = 128;
constexpr int SROW = 40;  // sbuf row stride (32 + 8 pad, keeps 16B align)

typedef __attribute__((ext_vector_type(8))) short short8;
typedef __attribute__((ext_vector_type(4))) float floatx4;
typedef __attribute__((ext_vector_type(2))) float floatx2;

__device__ __forceinline__ float bfhi2f(unsigned u) {  // already-positioned bits
  return __uint_as_float(u);
}

// wTr[(wv*18 + s)*64*8 + lane*8 + j] = bf16(weight[o = 16wv + (lane&15)]
//                                           [kk = 32s + (lane>>4)*8 + j])
__global__ void prep_w(const float* __restrict__ w, ushort* __restrict__ wTr) {
  int i = blockIdx.x * blockDim.x + threadIdx.x;
  if (i >= 4 * NSTEP * 64 * 8) return;
  int j = i & 7;
  int lane = (i >> 3) & 63;
  int s = (i >> 9) % NSTEP;
  int wv = i / (512 * NSTEP);
  int o = wv * 16 + (lane & 15);
  int kk = s * 32 + (lane >> 4) * 8 + j;
  int tap = kk >> 6, c = kk & 63;
  __hip_bfloat16 b = __float2bfloat16(w[(o * CIN + c) * K2 + tap]);
  wTr[i] = *(ushort*)&b;
}

// x[n][c][hw] fp32 -> xt[n][hw][c] bf16, via LDS tile (64 px x 64 ch).
__global__ __launch_bounds__(256) void transpose_x(
    const float* __restrict__ x, ushort* __restrict__ xt) {
  __shared__ ushort tile[64 * 72];
  int b = blockIdx.x;
  int n = b >> 11;
  int hw0 = (b & 2047) * 64;
  int tid = threadIdx.x;
  int px = tid & 63, c4 = tid >> 6;
  const float* xn = x + (size_t)n * CIN * HW;
#pragma unroll
  for (int it = 0; it < 16; ++it) {
    int c = it * 4 + c4;
    float v = xn[(size_t)c * HW + hw0 + px];
    __hip_bfloat16 hb = __float2bfloat16(v);
    tile[px * 72 + c] = *(ushort*)&hb;
  }
  __syncthreads();
  ushort* xtn = xt + (size_t)n * HW * CIN;
#pragma unroll
  for (int it = 0; it < 2; ++it) {
    int task = it * 256 + tid;
    int px2 = task >> 3, chunk = task & 7;
    uint4 v = *(uint4*)&tile[px2 * 72 + chunk * 8];
    *(uint4*)&xtn[(size_t)(hw0 + px2) * 64 + chunk * 8] = v;
  }
}

__global__ __launch_bounds__(256, 3) void sphere_conv_mfma(
    const ushort* __restrict__ xt, const ushort* __restrict__ wTr,
    const float* __restrict__ pos, float* __restrict__ out) {
  __shared__ int off_lds[K2 * PTILE];          // 4.6 KB packed o00|dx<<20|dy<<21
  __shared__ uint2 wgt_lds[K2 * PTILE];        // 9.2 KB: 4 corner wgts in bf16
  __shared__ ushort sbuf[2][PTILE * SROW];     // 20 KB: double-buffered S tile

  int tid = threadIdx.x;
  int blk = blockIdx.x;
  int n = blk >> 10;
  int ptile = (blk & 1023) * PTILE;

  // ---- phase 0: bilinear offsets/weights for 9 taps x 128 pixels ----
  for (int i = tid; i < K2 * PTILE; i += 256) {
    int t = i / PTILE, p = i - t * PTILE;
    int hw = ptile + p;
    float py = pos[(2 * t + 0) * HW + hw];
    float px = pos[(2 * t + 1) * HW + hw];
    float y0f = floorf(py), x0f = floorf(px);
    float dy = py - y0f, dx = px - x0f;
    float y1f = y0f + 1.f, x1f = x0f + 1.f;
    float vy0 = (y0f >= 0.f && y0f <= (float)(H_ - 1)) ? 1.f : 0.f;
    float vy1 = (y1f >= 0.f && y1f <= (float)(H_ - 1)) ? 1.f : 0.f;
    float vx0 = (x0f >= 0.f && x0f <= (float)(W_ - 1)) ? 1.f : 0.f;
    float vx1 = (x1f >= 0.f && x1f <= (float)(W_ - 1)) ? 1.f : 0.f;
    float w00 = (1.f - dy) * (1.f - dx) * vy0 * vx0;
    float w01 = (1.f - dy) * dx * vy0 * vx1;
    float w10 = dy * (1.f - dx) * vy1 * vx0;
    float w11 = dy * dx * vy1 * vx1;
    int y0c = (int)fminf(fmaxf(y0f, 0.f), (float)(H_ - 1));
    int y1c = (int)fminf(fmaxf(y1f, 0.f), (float)(H_ - 1));
    int x0c = (int)fminf(fmaxf(x0f, 0.f), (float)(W_ - 1));
    int x1c = (int)fminf(fmaxf(x1f, 0.f), (float)(W_ - 1));
    int o00 = y0c * W_ + x0c;
    off_lds[i] = o00 | ((x1c - x0c) << 20) | ((y1c - y0c) << 21);
    __hip_bfloat16 b00 = __float2bfloat16(w00), b01 = __float2bfloat16(w01);
    __hip_bfloat16 b10 = __float2bfloat16(w10), b11 = __float2bfloat16(w11);
    unsigned lo = ((unsigned)*(ushort*)&b01 << 16) | *(ushort*)&b00;
    unsigned hi = ((unsigned)*(ushort*)&b11 << 16) | *(ushort*)&b10;
    wgt_lds[i] = make_uint2(lo, hi);
  }

  int lane = tid & 63, wv = tid >> 6;
  int col = lane & 15, quad = lane >> 4;
  int px_s = tid >> 1, hf = tid & 1;  // sampling: pixel, channel-16 half

  floatx4 acc[8];
#pragma unroll
  for (int nt = 0; nt < 8; ++nt) acc[nt] = (floatx4)0.f;

  const ushort* xtn = xt + (size_t)n * HW * CIN;

  __syncthreads();

  // stage-load: off/wgt decode + 8 gather loads for step s
  auto gather = [&](int s, short8 g[8], float w4[4]) {
    int t = s >> 1;
    int c0 = ((s & 1) << 5) + (hf << 4);
    int pk = off_lds[t * PTILE + px_s];
    uint2 wr = wgt_lds[t * PTILE + px_s];
    w4[0] = bfhi2f(wr.x << 16);
    w4[1] = bfhi2f(wr.x & 0xFFFF0000u);
    w4[2] = bfhi2f(wr.y << 16);
    w4[3] = bfhi2f(wr.y & 0xFFFF0000u);
    int o00 = pk & 0x1FFFF;
    int dx1 = (pk >> 20) & 1;
    int dyW = ((pk >> 21) & 1) * W_;
    const ushort* base = xtn + c0;
    const ushort* p00 = base + (size_t)o00 * 64;
    const ushort* p01 = p00 + dx1 * 64;
    const ushort* p10 = p00 + dyW * 64;
    const ushort* p11 = p10 + dx1 * 64;
    g[0] = *(const short8*)p00; g[1] = *(const short8*)(p00 + 8);
    g[2] = *(const short8*)p01; g[3] = *(const short8*)(p01 + 8);
    g[4] = *(const short8*)p10; g[5] = *(const short8*)(p10 + 8);
    g[6] = *(const short8*)p11; g[7] = *(const short8*)(p11 + 8);
  };

  short8 gA[8];
  float wA[4];
  gather(0, gA, wA);

#pragma unroll
  for (int s = 0; s < NSTEP; ++s) {
    short8 gB[8];
    float wB[4];
    if (s + 1 < NSTEP) gather(s + 1, gB, wB);  // prefetch next stage

    // ---- interp current stage (pk f32 math), write sbuf[s&1] ----
    const unsigned* u = (const unsigned*)gA;  // 32 dwords: corner c at u[8c+d]
    floatx2 a2[8];
#pragma unroll
    for (int d = 0; d < 8; ++d) {
      floatx2 f = {bfhi2f(u[d] << 16), bfhi2f(u[d] & 0xFFFF0000u)};
      a2[d] = floatx2{wA[0], wA[0]} * f;
    }
#pragma unroll
    for (int c = 1; c < 4; ++c) {
#pragma unroll
      for (int d = 0; d < 8; ++d) {
        unsigned v = u[c * 8 + d];
        floatx2 f = {bfhi2f(v << 16), bfhi2f(v & 0xFFFF0000u)};
        a2[d] = __builtin_elementwise_fma(floatx2{wA[c], wA[c]}, f, a2[d]);
      }
    }
    __align__(16) unsigned tmp[8];
#pragma unroll
    for (int d = 0; d < 8; ++d) {
      __hip_bfloat16 lo = __float2bfloat16(a2[d].x);
      __hip_bfloat16 hi = __float2bfloat16(a2[d].y);
      tmp[d] = ((unsigned)*(ushort*)&hi << 16) | *(ushort*)&lo;
    }
    uint4* dst = (uint4*)&sbuf[s & 1][px_s * SROW + hf * 16];
    dst[0] = ((const uint4*)tmp)[0];
    dst[1] = ((const uint4*)tmp)[1];

    __syncthreads();  // single barrier: write(s) before read(s); write(s+2)
                      // to same buffer is fenced by barrier(s+1).

    short8 afrag = *(const short8*)(wTr + ((wv * NSTEP + s) * 64 + lane) * 8);
#pragma unroll
    for (int nt = 0; nt < 8; ++nt) {
      short8 bfrag = *(const short8*)&sbuf[s & 1][(nt * 16 + col) * SROW + quad * 8];
      acc[nt] = __builtin_amdgcn_mfma_f32_16x16x32_bf16(afrag, bfrag, acc[nt], 0, 0, 0);
    }

    if (s + 1 < NSTEP) {
#pragma unroll
      for (int q = 0; q < 8; ++q) gA[q] = gB[q];
#pragma unroll
      for (int q = 0; q < 4; ++q) wA[q] = wB[q];
    }
  }

  // ---- epilogue: D row = quad*4+r (COUT), col = lane&15 (pixel) ----
#pragma unroll
  for (int nt = 0; nt < 8; ++nt) {
#pragma unroll
    for (int r = 0; r < 4; ++r) {
      int o = wv * 16 + quad * 4 + r;
      out[(size_t)(n * COUT + o) * HW + ptile + nt * 16 + col] = acc[nt][r];
    }
  }
}

extern "C" void kernel_launch(void* const* d_in, const int* in_sizes, int n_in,
                              void* d_out, int out_size, void* d_ws, size_t ws_size,
                              hipStream_t stream) {
  const float* x   = (const float*)d_in[0];  // (2, 64, 256, 512) fp32
  const float* w   = (const float*)d_in[1];  // (64, 64, 3, 3) fp32
  const float* pos = (const float*)d_in[2];  // (18, 256, 512) fp32
  float* out = (float*)d_out;                // (2, 64, 256, 512) fp32

  // ws layout: wTr bf16 [72 KB] at 0; xt bf16 [67.1 MB] at 128 KB.
  ushort* wTr = (ushort*)d_ws;
  ushort* xt = (ushort*)((char*)d_ws + (128 << 10));

  prep_w<<<(4 * NSTEP * 64 * 8 + 255) / 256, 256, 0, stream>>>(w, wTr);
  transpose_x<<<N_ * (HW / 64), 256, 0, stream>>>(x, xt);

  int nblk = N_ * (HW / PTILE);  // 2048
  sphere_conv_mfma<<<nblk, 256, 0, stream>>>(xt, wTr, pos, out);
}